// Round 1
// baseline (43970.233 us; speedup 1.0000x reference)
//
#include <hip/hip_runtime.h>
#include <math.h>

#define Bsz 256
#define Tsz 512
#define Dsz 64
#define Hsz 256

__device__ __forceinline__ float sigm(float x) { return 1.0f / (1.0f + __expf(-x)); }

// 4-wide dot-product step for two batch elements sharing the same weight vector
__device__ __forceinline__ void dot4x2(const float4 w, const float4 a, const float4 b,
                                       float& za, float& zb) {
    za = fmaf(w.x, a.x, za); za = fmaf(w.y, a.y, za);
    za = fmaf(w.z, a.z, za); za = fmaf(w.w, a.w, za);
    zb = fmaf(w.x, b.x, zb); zb = fmaf(w.y, b.y, zb);
    zb = fmaf(w.z, b.z, zb); zb = fmaf(w.w, b.w, zb);
}

// One block = 2 batch elements, full 2-layer LSTM recurrence fused.
// Thread j owns hidden column j: gate rows j (i), j+H (f), j+2H (g), j+3H (o).
__global__ __launch_bounds__(256)
void lstm2_fused(const float* __restrict__ x,
                 const float* __restrict__ Wih0, const float* __restrict__ Whh0,
                 const float* __restrict__ bih0, const float* __restrict__ bhh0,
                 const float* __restrict__ Wih1, const float* __restrict__ Whh1,
                 const float* __restrict__ bih1, const float* __restrict__ bhh1,
                 const float* __restrict__ Wf,   const float* __restrict__ bf,
                 float* __restrict__ out)
{
    const int j  = threadIdx.x;        // hidden column 0..255
    const int b0 = blockIdx.x * 2;     // two batch elements per block

    __shared__ __align__(16) float h0s[2][Hsz];
    __shared__ __align__(16) float h1s[2][Hsz];
    __shared__ __align__(16) float xs[2][Dsz];
    __shared__ float red[2][4];

    // fused biases (bih + bhh), per gate
    const float bi0 = bih0[j]         + bhh0[j];
    const float bF0 = bih0[j + Hsz]   + bhh0[j + Hsz];
    const float bg0 = bih0[j + 2*Hsz] + bhh0[j + 2*Hsz];
    const float bo0 = bih0[j + 3*Hsz] + bhh0[j + 3*Hsz];
    const float bi1 = bih1[j]         + bhh1[j];
    const float bF1 = bih1[j + Hsz]   + bhh1[j + Hsz];
    const float bg1 = bih1[j + 2*Hsz] + bhh1[j + 2*Hsz];
    const float bo1 = bih1[j + 3*Hsz] + bhh1[j + 3*Hsz];

    // weight row pointers (rows are contiguous, 16B-aligned)
    const float4* wx_i = (const float4*)(Wih0 + (size_t)j * Dsz);
    const float4* wx_f = (const float4*)(Wih0 + (size_t)(j + Hsz)   * Dsz);
    const float4* wx_g = (const float4*)(Wih0 + (size_t)(j + 2*Hsz) * Dsz);
    const float4* wx_o = (const float4*)(Wih0 + (size_t)(j + 3*Hsz) * Dsz);

    const float4* w0_i = (const float4*)(Whh0 + (size_t)j * Hsz);
    const float4* w0_f = (const float4*)(Whh0 + (size_t)(j + Hsz)   * Hsz);
    const float4* w0_g = (const float4*)(Whh0 + (size_t)(j + 2*Hsz) * Hsz);
    const float4* w0_o = (const float4*)(Whh0 + (size_t)(j + 3*Hsz) * Hsz);

    const float4* w1x_i = (const float4*)(Wih1 + (size_t)j * Hsz);
    const float4* w1x_f = (const float4*)(Wih1 + (size_t)(j + Hsz)   * Hsz);
    const float4* w1x_g = (const float4*)(Wih1 + (size_t)(j + 2*Hsz) * Hsz);
    const float4* w1x_o = (const float4*)(Wih1 + (size_t)(j + 3*Hsz) * Hsz);

    const float4* w1_i = (const float4*)(Whh1 + (size_t)j * Hsz);
    const float4* w1_f = (const float4*)(Whh1 + (size_t)(j + Hsz)   * Hsz);
    const float4* w1_g = (const float4*)(Whh1 + (size_t)(j + 2*Hsz) * Hsz);
    const float4* w1_o = (const float4*)(Whh1 + (size_t)(j + 3*Hsz) * Hsz);

    // zero initial state
    h0s[0][j] = 0.f; h0s[1][j] = 0.f;
    h1s[0][j] = 0.f; h1s[1][j] = 0.f;
    float c00 = 0.f, c01 = 0.f, c10 = 0.f, c11 = 0.f;
    float h1v0 = 0.f, h1v1 = 0.f;   // register copies of layer-1 h for the epilogue

    for (int t = 0; t < Tsz; ++t) {
        // stage x[b, t, :] for both batch elements (2*64 = 128 threads)
        if (j < 2 * Dsz) {
            int bb = j >> 6, d = j & 63;
            xs[bb][d] = x[(size_t)(b0 + bb) * Tsz * Dsz + (size_t)t * Dsz + d];
        }
        __syncthreads();   // xs visible; also publishes prev-iter h1s writes

        // ---- phase A: all reads of h0(t-1), h1(t-1), xs ----
        float zi0 = bi0, zf0 = bF0, zg0 = bg0, zo0 = bo0;   // layer-0, batch 0
        float zi1 = bi0, zf1 = bF0, zg1 = bg0, zo1 = bo0;   // layer-0, batch 1

        const float4* xv0 = (const float4*)xs[0];
        const float4* xv1 = (const float4*)xs[1];
        for (int d4 = 0; d4 < Dsz / 4; ++d4) {
            float4 a = xv0[d4], b = xv1[d4];
            dot4x2(wx_i[d4], a, b, zi0, zi1);
            dot4x2(wx_f[d4], a, b, zf0, zf1);
            dot4x2(wx_g[d4], a, b, zg0, zg1);
            dot4x2(wx_o[d4], a, b, zo0, zo1);
        }

        const float4* h0p0 = (const float4*)h0s[0];
        const float4* h0p1 = (const float4*)h0s[1];
        for (int k4 = 0; k4 < Hsz / 4; ++k4) {
            float4 a = h0p0[k4], b = h0p1[k4];
            dot4x2(w0_i[k4], a, b, zi0, zi1);
            dot4x2(w0_f[k4], a, b, zf0, zf1);
            dot4x2(w0_g[k4], a, b, zg0, zg1);
            dot4x2(w0_o[k4], a, b, zo0, zo1);
        }

        // layer-1 recurrent part (reads h1(t-1)) — independent of layer-0 update
        float yi0 = bi1, yf0 = bF1, yg0 = bg1, yo0 = bo1;
        float yi1 = bi1, yf1 = bF1, yg1 = bg1, yo1 = bo1;
        const float4* h1p0 = (const float4*)h1s[0];
        const float4* h1p1 = (const float4*)h1s[1];
        for (int k4 = 0; k4 < Hsz / 4; ++k4) {
            float4 a = h1p0[k4], b = h1p1[k4];
            dot4x2(w1_i[k4], a, b, yi0, yi1);
            dot4x2(w1_f[k4], a, b, yf0, yf1);
            dot4x2(w1_g[k4], a, b, yg0, yg1);
            dot4x2(w1_o[k4], a, b, yo0, yo1);
        }
        __syncthreads();   // all reads of h0s/h1s done

        // ---- phase B: layer-0 cell update, publish h0(t) ----
        {
            float ii = sigm(zi0), ff = sigm(zf0), gg = tanhf(zg0), oo = sigm(zo0);
            c00 = ff * c00 + ii * gg;
            h0s[0][j] = oo * tanhf(c00);
            ii = sigm(zi1); ff = sigm(zf1); gg = tanhf(zg1); oo = sigm(zo1);
            c01 = ff * c01 + ii * gg;
            h0s[1][j] = oo * tanhf(c01);
        }
        __syncthreads();   // h0(t) visible

        // ---- phase C: layer-1 input projection from h0(t), then cell update ----
        for (int k4 = 0; k4 < Hsz / 4; ++k4) {
            float4 a = h0p0[k4], b = h0p1[k4];
            dot4x2(w1x_i[k4], a, b, yi0, yi1);
            dot4x2(w1x_f[k4], a, b, yf0, yf1);
            dot4x2(w1x_g[k4], a, b, yg0, yg1);
            dot4x2(w1x_o[k4], a, b, yo0, yo1);
        }
        {
            float ii = sigm(yi0), ff = sigm(yf0), gg = tanhf(yg0), oo = sigm(yo0);
            c10 = ff * c10 + ii * gg;
            h1v0 = oo * tanhf(c10);
            h1s[0][j] = h1v0;
            ii = sigm(yi1); ff = sigm(yf1); gg = tanhf(yg1); oo = sigm(yo1);
            c11 = ff * c11 + ii * gg;
            h1v1 = oo * tanhf(c11);
            h1s[1][j] = h1v1;
        }
        // next-iteration top-of-loop __syncthreads publishes h1s
    }

    // ---- epilogue: out[b] = h1_last · Wf + bf ----
    float wfj = Wf[j];
    float p0 = h1v0 * wfj;
    float p1 = h1v1 * wfj;
    #pragma unroll
    for (int off = 32; off > 0; off >>= 1) {
        p0 += __shfl_down(p0, off);
        p1 += __shfl_down(p1, off);
    }
    const int wave = j >> 6, lane = j & 63;
    if (lane == 0) { red[0][wave] = p0; red[1][wave] = p1; }
    __syncthreads();
    if (j == 0) out[b0]     = red[0][0] + red[0][1] + red[0][2] + red[0][3] + bf[0];
    if (j == 1) out[b0 + 1] = red[1][0] + red[1][1] + red[1][2] + red[1][3] + bf[0];
}

extern "C" void kernel_launch(void* const* d_in, const int* in_sizes, int n_in,
                              void* d_out, int out_size, void* d_ws, size_t ws_size,
                              hipStream_t stream) {
    const float* x    = (const float*)d_in[0];
    const float* Wih0 = (const float*)d_in[1];
    const float* Whh0 = (const float*)d_in[2];
    const float* bih0 = (const float*)d_in[3];
    const float* bhh0 = (const float*)d_in[4];
    const float* Wih1 = (const float*)d_in[5];
    const float* Whh1 = (const float*)d_in[6];
    const float* bih1 = (const float*)d_in[7];
    const float* bhh1 = (const float*)d_in[8];
    const float* Wf   = (const float*)d_in[9];
    const float* bf   = (const float*)d_in[10];
    float* out = (float*)d_out;

    hipLaunchKernelGGL(lstm2_fused, dim3(Bsz / 2), dim3(Hsz), 0, stream,
                       x, Wih0, Whh0, bih0, bhh0, Wih1, Whh1, bih1, bhh1, Wf, bf, out);
}

// Round 2
// 25068.816 us; speedup vs baseline: 1.7540x; 1.7540x over previous
//
#include <hip/hip_runtime.h>
#include <hip/hip_cooperative_groups.h>
#include <math.h>

namespace cg = cooperative_groups;

#define Bsz 256
#define Tsz 512
#define Dsz 64
#define Hsz 256
#define NBLK 256
#define NTHR 512

__device__ __forceinline__ float sigm(float x) { return 1.0f / (1.0f + __expf(-x)); }

__device__ __forceinline__ void dot4(const float4 w, const float4 v, float& a) {
    a = fmaf(w.x, v.x, a); a = fmaf(w.y, v.y, a);
    a = fmaf(w.z, v.z, a); a = fmaf(w.w, v.w, a);
}

// Weight-stationary cooperative 2-layer LSTM.
// Grid: 256 blocks = 32 row-slices (8 hidden cols each) x 8 batch-slices (32 batches,
// processed in 2 passes of 16). Block keeps its 8-col slice of Wih0/Whh0/Wih1/Whh1 in
// LDS (~109 KB, rows padded +4 floats for conflict-free broadcast reads). Hidden state
// exchanged via global double buffers; one grid.sync() per superstep with layer skew:
// superstep s does layer0 step s and layer1 step s-1.
__global__ __launch_bounds__(NTHR, 1)
void lstm2_coop(const float* __restrict__ x,
                const float* __restrict__ Wih0, const float* __restrict__ Whh0,
                const float* __restrict__ bih0, const float* __restrict__ bhh0,
                const float* __restrict__ Wih1, const float* __restrict__ Whh1,
                const float* __restrict__ bih1, const float* __restrict__ bhh1,
                const float* __restrict__ Wf,   const float* __restrict__ bf,
                float* __restrict__ out, float* __restrict__ hbuf)
{
    cg::grid_group grid = cg::this_grid();
    const int tid = threadIdx.x;
    const int rs  = blockIdx.x >> 3;   // row-slice: cols [rs*8, rs*8+8)
    const int bs  = blockIdx.x & 7;    // batch-slice: batches [bs*32, bs*32+32)

    // weights: [gate][col-in-slice][k], rows padded 64->68 / 256->260
    __shared__ __align__(16) float W0x[4][8][68];
    __shared__ __align__(16) float W0h[4][8][260];
    __shared__ __align__(16) float W1x[4][8][260];
    __shared__ __align__(16) float W1h[4][8][260];
    __shared__ __align__(16) float h0s[16][260];
    __shared__ __align__(16) float h1s[16][260];
    __shared__ __align__(16) float xs[16][68];
    __shared__ float zb0[4][8][16];
    __shared__ float zb1[4][8][16];

    float* h0buf = hbuf;                       // [2][Bsz][Hsz]
    float* h1buf = hbuf + 2 * Bsz * Hsz;       // [2][Bsz][Hsz]

    // init: zero h buffers (ws is poisoned 0xAA each launch), seed out with bf
    for (int i = blockIdx.x * NTHR + tid; i < 4 * Bsz * Hsz; i += NBLK * NTHR)
        hbuf[i] = 0.f;
    if (rs == 0 && tid < 32) out[bs * 32 + tid] = bf[0];

    // one-time weight load into LDS
    for (int idx = tid; idx < 4 * 8 * 64; idx += NTHR) {
        int g = idx >> 9, cc = (idx >> 6) & 7, k = idx & 63;
        W0x[g][cc][k] = Wih0[(size_t)(g * Hsz + rs * 8 + cc) * Dsz + k];
    }
    for (int idx = tid; idx < 4 * 8 * 256; idx += NTHR) {
        int g = idx >> 11, cc = (idx >> 8) & 7, k = idx & 255;
        size_t row = (size_t)(g * Hsz + rs * 8 + cc);
        W0h[g][cc][k] = Whh0[row * Hsz + k];
        W1x[g][cc][k] = Wih1[row * Hsz + k];
        W1h[g][cc][k] = Whh1[row * Hsz + k];
    }

    // compute-thread mapping: bb fastest -> h reads 2-way-bank-free, w reads broadcast
    const int bb = tid & 15, cc = (tid >> 4) & 7, g = tid >> 7;
    const int col = rs * 8 + cc;
    const float bias0 = bih0[g * Hsz + col] + bhh0[g * Hsz + col];
    const float bias1 = bih1[g * Hsz + col] + bhh1[g * Hsz + col];

    // update-thread mapping (tid < 128): owns cell state for (col uc, batch ub)
    const int uc = tid >> 4, ub = tid & 15;
    const int ucol = rs * 8 + uc;
    float c0[2] = {0.f, 0.f}, c1[2] = {0.f, 0.f}, h1last[2] = {0.f, 0.f};

    grid.sync();   // init + weight visibility (weights are block-local but cheap)

    for (int s = 0; s <= Tsz; ++s) {
        const int rp = (s + 1) & 1;   // parity holding h0[s-1]
        const int rq = s & 1;         // parity holding h1[s-2]
        for (int p = 0; p < 2; ++p) {
            const int bbase = bs * 32 + p * 16;

            // ---- stage h0[s-1], h1[s-2], x[.,s,.] into LDS ----
            {
                const int r = tid >> 5, c4 = tid & 31;
                const float4* s0 = (const float4*)(h0buf + ((size_t)rp * Bsz + bbase + r) * Hsz);
                *(float4*)&h0s[r][c4 * 4]        = s0[c4];
                *(float4*)&h0s[r][(c4 + 32) * 4] = s0[c4 + 32];
                const float4* s1 = (const float4*)(h1buf + ((size_t)rq * Bsz + bbase + r) * Hsz);
                *(float4*)&h1s[r][c4 * 4]        = s1[c4];
                *(float4*)&h1s[r][(c4 + 32) * 4] = s1[c4 + 32];
            }
            if (s < Tsz && tid < 256) {
                const int rr = tid >> 4, d4 = tid & 15;
                *(float4*)&xs[rr][d4 * 4] =
                    *(const float4*)(x + ((size_t)(bbase + rr) * Tsz + s) * Dsz + d4 * 4);
            }
            __syncthreads();

            // ---- gate dot products: thread computes z[g][col] for batch bb ----
            if (s < Tsz) {                       // layer 0, timestep s
                float a0 = bias0, a1 = 0.f, a2 = 0.f, a3 = 0.f;
                const float4* w = (const float4*)&W0x[g][cc][0];
                const float4* v = (const float4*)&xs[bb][0];
                #pragma unroll
                for (int k = 0; k < 16; k += 4) {
                    dot4(w[k], v[k], a0);     dot4(w[k+1], v[k+1], a1);
                    dot4(w[k+2], v[k+2], a2); dot4(w[k+3], v[k+3], a3);
                }
                const float4* wh = (const float4*)&W0h[g][cc][0];
                const float4* hv = (const float4*)&h0s[bb][0];
                #pragma unroll 4
                for (int k = 0; k < 64; k += 4) {
                    dot4(wh[k], hv[k], a0);     dot4(wh[k+1], hv[k+1], a1);
                    dot4(wh[k+2], hv[k+2], a2); dot4(wh[k+3], hv[k+3], a3);
                }
                zb0[g][cc][bb] = (a0 + a1) + (a2 + a3);
            }
            if (s >= 1) {                        // layer 1, timestep s-1 (input = h0[s-1])
                float a0 = bias1, a1 = 0.f, a2 = 0.f, a3 = 0.f;
                const float4* w1 = (const float4*)&W1x[g][cc][0];
                const float4* hv0 = (const float4*)&h0s[bb][0];
                #pragma unroll 4
                for (int k = 0; k < 64; k += 4) {
                    dot4(w1[k], hv0[k], a0);     dot4(w1[k+1], hv0[k+1], a1);
                    dot4(w1[k+2], hv0[k+2], a2); dot4(w1[k+3], hv0[k+3], a3);
                }
                const float4* w2 = (const float4*)&W1h[g][cc][0];
                const float4* hv1 = (const float4*)&h1s[bb][0];
                #pragma unroll 4
                for (int k = 0; k < 64; k += 4) {
                    dot4(w2[k], hv1[k], a0);     dot4(w2[k+1], hv1[k+1], a1);
                    dot4(w2[k+2], hv1[k+2], a2); dot4(w2[k+3], hv1[k+3], a3);
                }
                zb1[g][cc][bb] = (a0 + a1) + (a2 + a3);
            }
            __syncthreads();

            // ---- cell updates (128 threads own (col, batch) cells) ----
            if (tid < 128) {
                if (s < Tsz) {
                    float ii = sigm(zb0[0][uc][ub]);
                    float ff = sigm(zb0[1][uc][ub]);
                    float gg = tanhf(zb0[2][uc][ub]);
                    float oo = sigm(zb0[3][uc][ub]);
                    float c = ff * c0[p] + ii * gg; c0[p] = c;
                    h0buf[((size_t)(s & 1) * Bsz + bbase + ub) * Hsz + ucol] = oo * tanhf(c);
                }
                if (s >= 1) {
                    float ii = sigm(zb1[0][uc][ub]);
                    float ff = sigm(zb1[1][uc][ub]);
                    float gg = tanhf(zb1[2][uc][ub]);
                    float oo = sigm(zb1[3][uc][ub]);
                    float c = ff * c1[p] + ii * gg; c1[p] = c;
                    float h = oo * tanhf(c);
                    h1last[p] = h;
                    h1buf[((size_t)((s + 1) & 1) * Bsz + bbase + ub) * Hsz + ucol] = h;
                }
            }
            // no barrier needed: next pass's stage touches h0s/h1s/xs only, and all
            // reads of those completed before the z-write barrier above; zb is only
            // rewritten after the next pass's stage barrier, which update threads
            // reach only after finishing their zb reads.
        }
        grid.sync();
    }

    // ---- epilogue: out[b] = sum_col h1_final[b][col] * Wf[col] + bf ----
    if (tid < 128) {
        const float wf = Wf[ucol];
        atomicAdd(&out[bs * 32 + ub],      h1last[0] * wf);
        atomicAdd(&out[bs * 32 + 16 + ub], h1last[1] * wf);
    }
}

extern "C" void kernel_launch(void* const* d_in, const int* in_sizes, int n_in,
                              void* d_out, int out_size, void* d_ws, size_t ws_size,
                              hipStream_t stream) {
    const float* x    = (const float*)d_in[0];
    const float* Wih0 = (const float*)d_in[1];
    const float* Whh0 = (const float*)d_in[2];
    const float* bih0 = (const float*)d_in[3];
    const float* bhh0 = (const float*)d_in[4];
    const float* Wih1 = (const float*)d_in[5];
    const float* Whh1 = (const float*)d_in[6];
    const float* bih1 = (const float*)d_in[7];
    const float* bhh1 = (const float*)d_in[8];
    const float* Wf   = (const float*)d_in[9];
    const float* bf   = (const float*)d_in[10];
    float* out  = (float*)d_out;
    float* hbuf = (float*)d_ws;   // needs 4*Bsz*Hsz floats = 1 MB

    void* args[] = {
        (void*)&x, (void*)&Wih0, (void*)&Whh0, (void*)&bih0, (void*)&bhh0,
        (void*)&Wih1, (void*)&Whh1, (void*)&bih1, (void*)&bhh1,
        (void*)&Wf, (void*)&bf, (void*)&out, (void*)&hbuf
    };
    hipLaunchCooperativeKernel((void*)lstm2_coop, dim3(NBLK), dim3(NTHR),
                               args, 0, stream);
}

// Round 3
// 12723.193 us; speedup vs baseline: 3.4559x; 1.9703x over previous
//
#include <hip/hip_runtime.h>
#include <hip/hip_cooperative_groups.h>
#include <math.h>

namespace cg = cooperative_groups;

#define Tsz 512
#define NBLK 256
#define NTHR 512

__device__ __forceinline__ float sigm(float x) { return 1.0f / (1.0f + __expf(-x)); }

// acc[ri][ci] += w[ri] * h[ci]  (rows x batches 4x4 tile)
__device__ __forceinline__ void fma16(const float4 w, const float4 h, float (&a)[4][4]) {
    a[0][0] = fmaf(w.x, h.x, a[0][0]); a[0][1] = fmaf(w.x, h.y, a[0][1]);
    a[0][2] = fmaf(w.x, h.z, a[0][2]); a[0][3] = fmaf(w.x, h.w, a[0][3]);
    a[1][0] = fmaf(w.y, h.x, a[1][0]); a[1][1] = fmaf(w.y, h.y, a[1][1]);
    a[1][2] = fmaf(w.y, h.z, a[1][2]); a[1][3] = fmaf(w.y, h.w, a[1][3]);
    a[2][0] = fmaf(w.z, h.x, a[2][0]); a[2][1] = fmaf(w.z, h.y, a[2][1]);
    a[2][2] = fmaf(w.z, h.z, a[2][2]); a[2][3] = fmaf(w.z, h.w, a[2][3]);
    a[3][0] = fmaf(w.w, h.x, a[3][0]); a[3][1] = fmaf(w.w, h.y, a[3][1]);
    a[3][2] = fmaf(w.w, h.z, a[3][2]); a[3][3] = fmaf(w.w, h.w, a[3][3]);
}

// Weight-stationary 2-layer LSTM, register-tiled GEMM, k-slice = wave index.
// 256 blocks = 32 row-slices (8 hidden cols) x 8 batch-slices (32 batches, 2 passes of 16).
// Merged GEMM per pass: M=64 rows (lanes 0..31 -> layer0 rows, 32..63 -> layer1 rows),
// N=16 batches, K interleaved stride 8 across the 8 waves. Cross-wave partials tree-
// reduced via 16KB LDS. Per-batch-slice 32-block barrier (monotone counter) per superstep.
__global__ __launch_bounds__(NTHR, 1)
void lstm2_ws(const float* __restrict__ x,
              const float* __restrict__ Wih0, const float* __restrict__ Whh0,
              const float* __restrict__ bih0, const float* __restrict__ bhh0,
              const float* __restrict__ Wih1, const float* __restrict__ Whh1,
              const float* __restrict__ bih1, const float* __restrict__ bhh1,
              const float* __restrict__ Wf,   const float* __restrict__ bf,
              float* __restrict__ out, float* __restrict__ ws)
{
    cg::grid_group grid = cg::this_grid();
    const int tid = threadIdx.x;
    const int rs  = blockIdx.x >> 3;   // row-slice: cols [rs*8, rs*8+8)
    const int bs  = blockIdx.x & 7;    // batch-slice: batches [bs*32, bs*32+32)

    // Transposed weights: W0T[k][r]: k<256 = Whh0 col k, k>=256 = Wih0 col k-256.
    //                     W1T[k][r]: k<256 = Wih1 col k, k>=256 = Whh1 col k-256.
    // r = g*8 + cc (4 gates x 8 cols of this row-slice).
    __shared__ float W0T[320][32];     // 40 KB
    __shared__ float W1T[512][32];     // 64 KB
    __shared__ float h0sT[256][16];    // 16 KB  [col][batch-in-pass]
    __shared__ float h1sT[256][16];    // 16 KB
    __shared__ float xs[16][69];       // 4.3 KB [batch][d], padded
    __shared__ float zred[16][257];    // 16.4 KB reduction buffer; zfinal aliases it
    float* zf = &zred[0][0];           // zfinal(R,b) = zf[17*R + b], R<64, b<16

    float* h0buf = ws;                         // [2][256 cols][256 batches]
    float* h1buf = ws + 2 * 256 * 256;
    unsigned* cnt = (unsigned*)(ws + 4 * 256 * 256);   // [8] group barrier counters

    // ---- init (ws re-poisoned each launch) ----
    for (int i = blockIdx.x * NTHR + tid; i < 4 * 256 * 256; i += NBLK * NTHR) ws[i] = 0.f;
    if (blockIdx.x == 0 && tid < 8) cnt[tid] = 0u;
    if (rs == 0 && tid < 32) out[bs * 32 + tid] = bf[0];

    // ---- one-time weight stage (transposed) ----
    for (int idx = tid; idx < 26624; idx += NTHR) {
        if (idx < 10240) {                   // W0T: 320*32
            int k = idx >> 5, r = idx & 31;
            int grow = (r >> 3) * 256 + rs * 8 + (r & 7);
            W0T[k][r] = (k < 256) ? Whh0[(size_t)grow * 256 + k]
                                  : Wih0[(size_t)grow * 64 + (k - 256)];
        } else {                             // W1T: 512*32
            int i2 = idx - 10240;
            int k = i2 >> 5, r = i2 & 31;
            int grow = (r >> 3) * 256 + rs * 8 + (r & 7);
            W1T[k][r] = (k < 256) ? Wih1[(size_t)grow * 256 + k]
                                  : Whh1[(size_t)grow * 256 + (k - 256)];
        }
    }

    // ---- GEMM lane decode ----
    const int lane = tid & 63, wv = tid >> 6;      // wv = wave = k-slice
    const int rt = lane >> 2, ct = lane & 3;       // rt 0..15 (rows 4rt..), ct 0..3 (batches 4ct..)
    const bool up = rt >= 8;                       // layer-1 lanes

    // ---- updater decode (tid < 256): owns cell (layer ul, col cc, batch b) ----
    const int ul = tid >> 7, ucc = (tid >> 4) & 7, ub = tid & 15;
    const int ucol = rs * 8 + ucc;
    float ubias[4];
    if (tid < 256) {
        const float* bi = ul ? bih1 : bih0;
        const float* bh = ul ? bhh1 : bhh0;
        #pragma unroll
        for (int g = 0; g < 4; ++g) ubias[g] = bi[g * 256 + ucol] + bh[g * 256 + ucol];
    }
    float c0[2] = {0.f, 0.f}, c1[2] = {0.f, 0.f}, h1last[2] = {0.f, 0.f};

    grid.sync();   // init + weights (weights block-local; this also orders cnt/out/hbuf)

    for (int s = 0; s <= Tsz; ++s) {
        const int rp = (s + 1) & 1;   // parity holding h0[s-1]
        const int rq = s & 1;         // parity holding h1[s-2]
        #pragma unroll
        for (int p = 0; p < 2; ++p) {
            const int bbase = bs * 32 + p * 16;

            // ---- stage h0[s-1], h1[s-2] (transposed copy), x[.,s,.] ----
            {
                const int b = tid & 15, c0i = tid >> 4;   // c0i 0..31
                #pragma unroll
                for (int i = 0; i < 8; ++i) {
                    int col = c0i + 32 * i;
                    h0sT[col][b] = h0buf[(size_t)(rp * 256 + col) * 256 + bbase + b];
                    h1sT[col][b] = h1buf[(size_t)(rq * 256 + col) * 256 + bbase + b];
                }
            }
            if (s < Tsz && tid < 256) {
                const int bb = tid >> 4, d4 = (tid & 15) * 4;
                const float4 xv = *(const float4*)(x + ((size_t)(bbase + bb) * Tsz + s) * 64 + d4);
                xs[bb][d4 + 0] = xv.x; xs[bb][d4 + 1] = xv.y;
                xs[bb][d4 + 2] = xv.z; xs[bb][d4 + 3] = xv.w;
            }
            __syncthreads();   // S1

            // ---- GEMM: acc[4][4], k = 8j + wv ----
            float acc[4][4];
            #pragma unroll
            for (int i = 0; i < 4; ++i)
                #pragma unroll
                for (int jj = 0; jj < 4; ++jj) acc[i][jj] = 0.f;

            // phase 1 (k 0..255): both halves read h0sT; W0T/W1T per half
            {
                const float* pw = (up ? &W1T[0][0] + 4 * (rt - 8) : &W0T[0][0] + 4 * rt)
                                  + wv * 32;
                const float* ph = &h0sT[0][0] + wv * 16 + 4 * ct;
                #pragma unroll 4
                for (int j = 0; j < 32; ++j) {
                    float4 w4 = *(const float4*)pw;
                    float4 h4 = *(const float4*)ph;
                    fma16(w4, h4, acc);
                    pw += 256; ph += 128;
                }
            }
            // phase 2: layer1 lanes: k 256..511 vs h1sT ; layer0 lanes: x-projection
            if (up) {
                const float* pw = &W1T[256][0] + 4 * (rt - 8) + wv * 32;
                const float* ph = &h1sT[0][0] + wv * 16 + 4 * ct;
                #pragma unroll 4
                for (int j = 0; j < 32; ++j) {
                    float4 w4 = *(const float4*)pw;
                    float4 h4 = *(const float4*)ph;
                    fma16(w4, h4, acc);
                    pw += 256; ph += 128;
                }
            } else {
                const float* pw = &W0T[256][0] + 4 * rt + wv * 32;
                const float* px = &xs[4 * ct][0] + wv;
                #pragma unroll
                for (int j = 0; j < 8; ++j) {
                    float4 w4 = *(const float4*)pw;
                    float4 h4;
                    h4.x = px[0]; h4.y = px[69]; h4.z = px[138]; h4.w = px[207];
                    fma16(w4, h4, acc);
                    pw += 256; px += 8;
                }
            }

            // ---- cross-wave tree reduction (8 -> 4 -> 2 -> 1 waves) ----
            if (tid >= 256) {                       // waves 4..7 write partials
                #pragma unroll
                for (int v = 0; v < 16; ++v) zred[v][tid - 256] = acc[v >> 2][v & 3];
            }
            __syncthreads();   // S2
            if (tid < 256) {
                #pragma unroll
                for (int v = 0; v < 16; ++v) acc[v >> 2][v & 3] += zred[v][tid];
            }
            if (tid >= 128 && tid < 256) {          // waves 2,3 write at own tid
                #pragma unroll
                for (int v = 0; v < 16; ++v) zred[v][tid] = acc[v >> 2][v & 3];
            }
            __syncthreads();   // S3
            if (tid < 128) {
                #pragma unroll
                for (int v = 0; v < 16; ++v) acc[v >> 2][v & 3] += zred[v][tid + 128];
            }
            if (tid >= 64 && tid < 128) {           // wave 1 writes at own tid
                #pragma unroll
                for (int v = 0; v < 16; ++v) zred[v][tid] = acc[v >> 2][v & 3];
            }
            __syncthreads();   // S4
            if (tid < 64) {                          // wave 0 finalizes + writes zfinal
                #pragma unroll
                for (int v = 0; v < 16; ++v) acc[v >> 2][v & 3] += zred[v][tid + 64];
                #pragma unroll
                for (int m = 0; m < 16; ++m) {       // ci permuted by rt: 2-way banks
                    int ri = m >> 2, ci = (m + rt) & 3;
                    zf[17 * (4 * rt + ri) + 4 * ct + ci] = acc[ri][ci];
                }
            }
            __syncthreads();   // S5

            // ---- cell update (tid < 256) ----
            if (tid < 256) {
                const bool active = ul ? (s >= 1) : (s < Tsz);
                if (active) {
                    const int Rb = ul * 32 + ucc;
                    float z0 = zf[17 * (Rb + 0)  + ub] + ubias[0];
                    float z1 = zf[17 * (Rb + 8)  + ub] + ubias[1];
                    float z2 = zf[17 * (Rb + 16) + ub] + ubias[2];
                    float z3 = zf[17 * (Rb + 24) + ub] + ubias[3];
                    float ii = sigm(z0), ff = sigm(z1), gg = tanhf(z2), oo = sigm(z3);
                    if (ul) {
                        float c = ff * c1[p] + ii * gg; c1[p] = c;
                        float h = oo * tanhf(c);
                        h1last[p] = h;
                        h1buf[(size_t)(((s + 1) & 1) * 256 + ucol) * 256 + bbase + ub] = h;
                    } else {
                        float c = ff * c0[p] + ii * gg; c0[p] = c;
                        h0buf[(size_t)((s & 1) * 256 + ucol) * 256 + bbase + ub] = oo * tanhf(c);
                    }
                }
            }
            // no sync needed here: next pass staging touches h0sT/h1sT/xs only; zred
            // is next written by waves 4..7 only after S1 of the next pass.
        }

        // ---- 32-block group barrier (blocks sharing bs) ----
        __syncthreads();
        if (tid == 0) {
            __threadfence();                          // release h writes (device scope)
            atomicAdd(&cnt[bs], 1u);
            const unsigned tgt = 32u * (unsigned)(s + 1);
            while (__hip_atomic_load(&cnt[bs], __ATOMIC_RELAXED, __HIP_MEMORY_SCOPE_AGENT) < tgt)
                __builtin_amdgcn_s_sleep(2);
            __threadfence();                          // acquire
        }
        __syncthreads();
    }

    // ---- epilogue: out[b] += sum_cols h1_final * Wf ----
    if (tid >= 128 && tid < 256) {       // layer-1 updaters
        const float wf = Wf[ucol];
        atomicAdd(&out[bs * 32 + ub],      h1last[0] * wf);
        atomicAdd(&out[bs * 32 + 16 + ub], h1last[1] * wf);
    }
}

extern "C" void kernel_launch(void* const* d_in, const int* in_sizes, int n_in,
                              void* d_out, int out_size, void* d_ws, size_t ws_size,
                              hipStream_t stream) {
    const float* x    = (const float*)d_in[0];
    const float* Wih0 = (const float*)d_in[1];
    const float* Whh0 = (const float*)d_in[2];
    const float* bih0 = (const float*)d_in[3];
    const float* bhh0 = (const float*)d_in[4];
    const float* Wih1 = (const float*)d_in[5];
    const float* Whh1 = (const float*)d_in[6];
    const float* bih1 = (const float*)d_in[7];
    const float* bhh1 = (const float*)d_in[8];
    const float* Wf   = (const float*)d_in[9];
    const float* bf   = (const float*)d_in[10];
    float* out = (float*)d_out;
    float* ws  = (float*)d_ws;   // 1 MB h buffers + 32 B barrier counters

    void* args[] = {
        (void*)&x, (void*)&Wih0, (void*)&Whh0, (void*)&bih0, (void*)&bhh0,
        (void*)&Wih1, (void*)&Whh1, (void*)&bih1, (void*)&bhh1,
        (void*)&Wf, (void*)&bf, (void*)&out, (void*)&ws
    };
    hipLaunchCooperativeKernel((void*)lstm2_ws, dim3(NBLK), dim3(NTHR),
                               args, 0, stream);
}

// Round 5
// 9552.193 us; speedup vs baseline: 4.6032x; 1.3320x over previous
//
#include <hip/hip_runtime.h>
#include <hip/hip_cooperative_groups.h>
#include <math.h>

namespace cg = cooperative_groups;

#define Tsz 512
#define NBLK 256
#define NTHR 512

typedef short short8  __attribute__((ext_vector_type(8)));
typedef short short4v __attribute__((ext_vector_type(4)));
typedef float float4v __attribute__((ext_vector_type(4)));

#define MFMA16(a, b, c) __builtin_amdgcn_mfma_f32_16x16x32_bf16((a), (b), (c), 0, 0, 0)

__device__ __forceinline__ float sigm(float x) { return 1.0f / (1.0f + __expf(-x)); }
__device__ __forceinline__ float tanh_fast(float x) { return 2.0f / (1.0f + __expf(-2.0f * x)) - 1.0f; }

// fp32 -> bf16 hi (x) + bf16 lo (y), RNE both: v ~= hi + lo, error ~2^-17 rel
__device__ __forceinline__ short2 split1(float f) {
    unsigned u = __float_as_uint(f);
    unsigned r = u + 0x7FFFu + ((u >> 16) & 1u);
    short h = (short)(r >> 16);
    float hf = __uint_as_float(r & 0xFFFF0000u);
    float d  = f - hf;
    unsigned u2 = __float_as_uint(d);
    unsigned r2 = u2 + 0x7FFFu + ((u2 >> 16) & 1u);
    return make_short2(h, (short)(r2 >> 16));
}

// Weight-stationary 2-layer LSTM via bf16-split-3 MFMA.
// 256 blocks = 32 row-slices (8 cols) x 8 batch-slices (32 batches, 2 passes of 16).
// M=64 rows (L0 rows 0..31: g*8+cc, L1 rows 32..63), N=16, K: L0=320 (h0|x), L1=512 (h0|h1).
// 4 16x16 tiles x 2 k-halves = 8 waves; z = Ah*Bh + Ah*Bl + Al*Bh (lo*lo dropped).
// Weights hi/lo bf16 in LDS (once); h staged hi/lo per pass; zpart pair-combine; skewed
// layers (superstep s: L0 step s, L1 step s-1); per-bs 32-block monotone-counter barrier.
__global__ __launch_bounds__(NTHR, 1)
void lstm2_mfma(const float* __restrict__ x,
                const float* __restrict__ Wih0, const float* __restrict__ Whh0,
                const float* __restrict__ bih0, const float* __restrict__ bhh0,
                const float* __restrict__ Wih1, const float* __restrict__ Whh1,
                const float* __restrict__ bih1, const float* __restrict__ bhh1,
                const float* __restrict__ Wf,   const float* __restrict__ bf,
                float* __restrict__ out, float* __restrict__ ws)
{
    cg::grid_group grid = cg::this_grid();
    const int tid = threadIdx.x;
    const int rs  = blockIdx.x >> 3;
    const int bs  = blockIdx.x & 7;

    // A planes: L0 rows m<32 at m*328 (320 k used), L1 rows at 10496+(m-32)*520 (512 k).
    // B planes: h0ext at n*328 (k<256: h0, 256..319: x); h1 at 5248 + n*264.
    // Pitches: 328*2B=656B=164dw =4 mod 32; 520*2B=260dw =4 mod 32 -> free 2-way banks.
    __shared__ short Wh[2][27136];          // 108.5 KB
    __shared__ short Bh[2][9472];           // 37.9 KB
    __shared__ float zpart[4][64][4];       // 4 KB
    __shared__ float zf[64][17];            // 4.3 KB

    float* h0buf = ws;                          // [2][256 batch][256 col]
    float* h1buf = ws + 2 * 256 * 256;
    unsigned* cnt = (unsigned*)(ws + 4 * 256 * 256);

    // ---- init ----
    for (int i = blockIdx.x * NTHR + tid; i < 4 * 256 * 256; i += NBLK * NTHR) ws[i] = 0.f;
    if (blockIdx.x == 0 && tid < 8) cnt[tid] = 0u;
    if (rs == 0 && tid < 32) out[bs * 32 + tid] = bf[0];

    // ---- one-time weight stage: fp32 -> hi/lo bf16 planes ----
    for (int m = 0; m < 64; ++m) {
        const int L = m >> 5, wr = m & 31, g = wr >> 3, cc = wr & 7;
        const size_t grow = (size_t)(g * 256 + rs * 8 + cc);
        const int klen = L ? 512 : 320;
        const int base = L ? 10496 + (m - 32) * 520 : m * 328;
        for (int k = tid; k < klen; k += NTHR) {
            float w;
            if (!L) w = (k < 256) ? Whh0[grow * 256 + k] : Wih0[grow * 64 + (k - 256)];
            else    w = (k < 256) ? Wih1[grow * 256 + k] : Whh1[grow * 256 + (k - 256)];
            short2 hl = split1(w);
            Wh[0][base + k] = hl.x; Wh[1][base + k] = hl.y;
        }
    }

    // ---- mfma lane decode ----
    const int wv = tid >> 6, lane = tid & 63;
    const int mt = wv & 3, half = wv >> 2;          // tile, k-half
    const int quad = lane >> 4, n16 = lane & 15;
    const int rowA = 16 * mt + n16;
    const int aBase = (rowA < 32 ? rowA * 328 : 10496 + (rowA - 32) * 520) + quad * 8;
    const int bBase0 = n16 * 328 + quad * 8;
    const int bBase1 = 5248 + n16 * 264 + quad * 8;

    // ---- updater decode (tid < 256): layer ul, col ucc, batch ub ----
    const int ul = tid >> 7, ucc = tid & 7, ub = (tid >> 3) & 15;
    const int ucol = rs * 8 + ucc;
    float ubias[4];
    if (tid < 256) {
        const float* bi = ul ? bih1 : bih0;
        const float* bh = ul ? bhh1 : bhh0;
        #pragma unroll
        for (int g = 0; g < 4; ++g) ubias[g] = bi[g * 256 + ucol] + bh[g * 256 + ucol];
    }
    float c0[2] = {0.f, 0.f}, c1[2] = {0.f, 0.f}, h1last[2] = {0.f, 0.f};

    grid.sync();

    for (int s = 0; s <= Tsz; ++s) {
        const int rp = (s + 1) & 1;   // parity of h0[s-1]
        const int rq = s & 1;         // parity of h1[s-2]
        #pragma unroll
        for (int p = 0; p < 2; ++p) {
            const int bbase = bs * 32 + p * 16;

            // ---- stage h0[s-1], h1[s-2], x[.,s,.] -> hi/lo bf16 B-planes ----
            {
                const int sn = tid >> 5, sk = (tid & 31) * 8;
                const float* p0 = &h0buf[((size_t)(rp * 256) + bbase + sn) * 256 + sk];
                float4 a = *(const float4*)p0, b = *(const float4*)(p0 + 4);
                short8 hi, lo;
                short2 t;
                t = split1(a.x); hi[0] = t.x; lo[0] = t.y;
                t = split1(a.y); hi[1] = t.x; lo[1] = t.y;
                t = split1(a.z); hi[2] = t.x; lo[2] = t.y;
                t = split1(a.w); hi[3] = t.x; lo[3] = t.y;
                t = split1(b.x); hi[4] = t.x; lo[4] = t.y;
                t = split1(b.y); hi[5] = t.x; lo[5] = t.y;
                t = split1(b.z); hi[6] = t.x; lo[6] = t.y;
                t = split1(b.w); hi[7] = t.x; lo[7] = t.y;
                *(short8*)&Bh[0][sn * 328 + sk] = hi;
                *(short8*)&Bh[1][sn * 328 + sk] = lo;
                const float* p1 = &h1buf[((size_t)(rq * 256) + bbase + sn) * 256 + sk];
                a = *(const float4*)p1; b = *(const float4*)(p1 + 4);
                t = split1(a.x); hi[0] = t.x; lo[0] = t.y;
                t = split1(a.y); hi[1] = t.x; lo[1] = t.y;
                t = split1(a.z); hi[2] = t.x; lo[2] = t.y;
                t = split1(a.w); hi[3] = t.x; lo[3] = t.y;
                t = split1(b.x); hi[4] = t.x; lo[4] = t.y;
                t = split1(b.y); hi[5] = t.x; lo[5] = t.y;
                t = split1(b.z); hi[6] = t.x; lo[6] = t.y;
                t = split1(b.w); hi[7] = t.x; lo[7] = t.y;
                *(short8*)&Bh[0][5248 + sn * 264 + sk] = hi;
                *(short8*)&Bh[1][5248 + sn * 264 + sk] = lo;
            }
            if (s < Tsz && tid < 256) {
                const int xn = tid >> 4, d4 = (tid & 15) * 4;
                float4 xv = *(const float4*)&x[((size_t)(bbase + xn) * Tsz + s) * 64 + d4];
                short4v xh, xl;
                short2 t;
                t = split1(xv.x); xh[0] = t.x; xl[0] = t.y;
                t = split1(xv.y); xh[1] = t.x; xl[1] = t.y;
                t = split1(xv.z); xh[2] = t.x; xl[2] = t.y;
                t = split1(xv.w); xh[3] = t.x; xl[3] = t.y;
                *(short4v*)&Bh[0][xn * 328 + 256 + d4] = xh;
                *(short4v*)&Bh[1][xn * 328 + 256 + d4] = xl;
            }
            __syncthreads();   // S1

            // ---- MFMA: 16x16 tile mt, k-half ----
            float4v acc = {0.f, 0.f, 0.f, 0.f};
            if (mt < 2) {                       // layer 0: K=320, chunks half*5..+5
                const int k0 = half * 5 * 32;
                #pragma unroll
                for (int kc = 0; kc < 5; ++kc) {
                    const int ao = aBase + k0 + kc * 32;
                    const int bo = bBase0 + k0 + kc * 32;
                    short8 ah = *(const short8*)&Wh[0][ao];
                    short8 al = *(const short8*)&Wh[1][ao];
                    short8 bh2 = *(const short8*)&Bh[0][bo];
                    short8 bl2 = *(const short8*)&Bh[1][bo];
                    acc = MFMA16(ah, bh2, acc);
                    acc = MFMA16(ah, bl2, acc);
                    acc = MFMA16(al, bh2, acc);
                }
            } else if (half == 0) {             // layer 1, k 0..255 vs h0
                #pragma unroll
                for (int kc = 0; kc < 8; ++kc) {
                    const int ao = aBase + kc * 32;
                    const int bo = bBase0 + kc * 32;
                    short8 ah = *(const short8*)&Wh[0][ao];
                    short8 al = *(const short8*)&Wh[1][ao];
                    short8 bh2 = *(const short8*)&Bh[0][bo];
                    short8 bl2 = *(const short8*)&Bh[1][bo];
                    acc = MFMA16(ah, bh2, acc);
                    acc = MFMA16(ah, bl2, acc);
                    acc = MFMA16(al, bh2, acc);
                }
            } else {                            // layer 1, k 256..511 vs h1
                #pragma unroll
                for (int kc = 0; kc < 8; ++kc) {
                    const int ao = aBase + 256 + kc * 32;
                    const int bo = bBase1 + kc * 32;
                    short8 ah = *(const short8*)&Wh[0][ao];
                    short8 al = *(const short8*)&Wh[1][ao];
                    short8 bh2 = *(const short8*)&Bh[0][bo];
                    short8 bl2 = *(const short8*)&Bh[1][bo];
                    acc = MFMA16(ah, bh2, acc);
                    acc = MFMA16(ah, bl2, acc);
                    acc = MFMA16(al, bh2, acc);
                }
            }

            // ---- k-half combine + zf scatter ----
            if (half) *(float4v*)&zpart[mt][lane][0] = acc;
            __syncthreads();   // S2
            if (!half) {
                acc += *(const float4v*)&zpart[mt][lane][0];
                #pragma unroll
                for (int r = 0; r < 4; ++r)
                    zf[16 * mt + quad * 4 + r][n16] = acc[r];
            }
            __syncthreads();   // S3

            // ---- cell update ----
            if (tid < 256) {
                const bool active = ul ? (s >= 1) : (s < Tsz);
                if (active) {
                    const int mb = ul * 32 + ucc;
                    float z0 = zf[mb +  0][ub] + ubias[0];
                    float z1 = zf[mb +  8][ub] + ubias[1];
                    float z2 = zf[mb + 16][ub] + ubias[2];
                    float z3 = zf[mb + 24][ub] + ubias[3];
                    float ii = sigm(z0), ff = sigm(z1);
                    float gg = tanh_fast(z2), oo = sigm(z3);
                    if (ul) {
                        float c = ff * c1[p] + ii * gg; c1[p] = c;
                        float h = oo * tanh_fast(c);
                        h1last[p] = h;
                        h1buf[((size_t)(((s + 1) & 1) * 256) + bbase + ub) * 256 + ucol] = h;
                    } else {
                        float c = ff * c0[p] + ii * gg; c0[p] = c;
                        h0buf[((size_t)((s & 1) * 256) + bbase + ub) * 256 + ucol] =
                            oo * tanh_fast(c);
                    }
                }
            }
            // safe: next stage rewrites Bh only after S1; zpart/zf rewritten after S2.
        }

        // ---- 32-block group barrier (blocks sharing bs) ----
        __syncthreads();
        if (tid == 0) {
            __threadfence();
            atomicAdd(&cnt[bs], 1u);
            const unsigned tgt = 32u * (unsigned)(s + 1);
            while (__hip_atomic_load(&cnt[bs], __ATOMIC_RELAXED, __HIP_MEMORY_SCOPE_AGENT) < tgt)
                __builtin_amdgcn_s_sleep(2);
            __threadfence();
        }
        __syncthreads();
    }

    // ---- epilogue ----
    if (tid >= 128 && tid < 256) {
        const float wf = Wf[ucol];
        atomicAdd(&out[bs * 32 + ub],      h1last[0] * wf);
        atomicAdd(&out[bs * 32 + 16 + ub], h1last[1] * wf);
    }
}

extern "C" void kernel_launch(void* const* d_in, const int* in_sizes, int n_in,
                              void* d_out, int out_size, void* d_ws, size_t ws_size,
                              hipStream_t stream) {
    const float* x    = (const float*)d_in[0];
    const float* Wih0 = (const float*)d_in[1];
    const float* Whh0 = (const float*)d_in[2];
    const float* bih0 = (const float*)d_in[3];
    const float* bhh0 = (const float*)d_in[4];
    const float* Wih1 = (const float*)d_in[5];
    const float* Whh1 = (const float*)d_in[6];
    const float* bih1 = (const float*)d_in[7];
    const float* bhh1 = (const float*)d_in[8];
    const float* Wf   = (const float*)d_in[9];
    const float* bf   = (const float*)d_in[10];
    float* out = (float*)d_out;
    float* ws  = (float*)d_ws;   // 1 MB h buffers + barrier counters

    void* args[] = {
        (void*)&x, (void*)&Wih0, (void*)&Whh0, (void*)&bih0, (void*)&bhh0,
        (void*)&Wih1, (void*)&Whh1, (void*)&bih1, (void*)&bhh1,
        (void*)&Wf, (void*)&bf, (void*)&out, (void*)&ws
    };
    hipLaunchCooperativeKernel((void*)lstm2_mfma, dim3(NBLK), dim3(NTHR),
                               args, 0, stream);
}